// Round 2
// baseline (1217.488 us; speedup 1.0000x reference)
//
#include <hip/hip_runtime.h>

typedef unsigned short u16;
typedef __attribute__((ext_vector_type(8))) short short8;
typedef __attribute__((ext_vector_type(4))) float f32x4;

#define NPTS 1048576
#define HP 264  // sH row stride in elements (528 B, 16B-aligned)

__device__ __forceinline__ u16 f2b(float f) {
    unsigned int x = __float_as_uint(f);
    return (u16)((x + 0x7fffu + ((x >> 16) & 1u)) >> 16);
}
#define INV2PI 0.15915494309189535f
// sin with argument in revolutions; v_sin_f32 wants fract-reduced input
__device__ __forceinline__ float sinrev(float t) {
    t = t - floorf(t);
    return __builtin_amdgcn_sinf(t);
}

// ---------------- weight convert(fp32->bf16) + transpose/pad prepass ----------------
// ws layout (bf16 elements), WT[n][k] row-major in k:
//  WT1  @      0 : 256 x  64   (from W1  63x256, k>=63 -> 0)
//  WT2  @  16384 : 256 x 256   (from W2 256x256)
//  WT3  @  81920 : 256 x 256   (from W3 256x256)
//  WT4  @ 147456 :  16 x 256   (from W4 256x16)
//  WTc1 @ 151552 : 128 x  64   (from Wc1 42x128, k>=42 -> 0)
//  WTc2 @ 159744 :  16 x 128   (from Wc2 128x3, n>=3 -> 0)
__global__ void prep_weights(const float* __restrict__ W1, const float* __restrict__ W2,
                             const float* __restrict__ W3, const float* __restrict__ W4,
                             const float* __restrict__ Wc1, const float* __restrict__ Wc2,
                             u16* __restrict__ ws) {
    int i = blockIdx.x * 256 + threadIdx.x;
    if (i < 16384) { int n = i >> 6, k = i & 63;  ws[i]          = (k < 63) ? f2b(W1[k * 256 + n]) : (u16)0; return; }
    i -= 16384;
    if (i < 65536) { int n = i >> 8, k = i & 255; ws[16384 + i]  = f2b(W2[k * 256 + n]); return; }
    i -= 65536;
    if (i < 65536) { int n = i >> 8, k = i & 255; ws[81920 + i]  = f2b(W3[k * 256 + n]); return; }
    i -= 65536;
    if (i < 4096)  { int n = i >> 8, k = i & 255; ws[147456 + i] = f2b(W4[k * 16 + n]); return; }
    i -= 4096;
    if (i < 8192)  { int n = i >> 6, k = i & 63;  ws[151552 + i] = (k < 42) ? f2b(Wc1[k * 128 + n]) : (u16)0; return; }
    i -= 8192;
    if (i < 2048)  { int n = i >> 7, k = i & 127; ws[159744 + i] = (n < 3) ? f2b(Wc2[k * 3 + n]) : (u16)0; return; }
}

// ---------------- fused dense layer ----------------
// MFMA 16x16x32 bf16.  A frag: m=lane&15, k=(lane>>4)*8+j (contig 16B from sH row)
// B frag: n=lane&15, k=(lane>>4)*8+j (contig 16B from WT[n][k] in global)
// D: col(n)=lane&15, row(m)=(lane>>4)*4+reg.
// Wave (wm,wn): rows [wm*32, +32), cols [nbase, nbase+NTW*16). In-place sH update:
// all A-frag reads complete before the internal barrier, writes after it.
template <int K, int NTW, bool RELU>
__device__ __forceinline__ void dense(const u16* __restrict__ WT, const float* __restrict__ bias,
                                      u16 (*sH)[HP], int wm, int lr, int q, int nbase) {
    constexpr int NKT = K / 32;
    short8 aF[2][NKT];
#pragma unroll
    for (int rt = 0; rt < 2; ++rt)
#pragma unroll
        for (int kt = 0; kt < NKT; ++kt)
            aF[rt][kt] = *(const short8*)&sH[wm * 32 + rt * 16 + lr][kt * 32 + q * 8];
    __syncthreads();
#pragma unroll
    for (int nt = 0; nt < NTW; ++nt) {
        const int n = nbase + nt * 16 + lr;
        const u16* wrow = WT + (size_t)n * K + q * 8;
        short8 bF[NKT];
#pragma unroll
        for (int kt = 0; kt < NKT; ++kt) bF[kt] = *(const short8*)(wrow + kt * 32);
        const float bi = bias[n];
#pragma unroll
        for (int rt = 0; rt < 2; ++rt) {
            f32x4 acc = {0.f, 0.f, 0.f, 0.f};
#pragma unroll
            for (int kt = 0; kt < NKT; ++kt)
                acc = __builtin_amdgcn_mfma_f32_16x16x32_bf16(aF[rt][kt], bF[kt], acc, 0, 0, 0);
#pragma unroll
            for (int r = 0; r < 4; ++r) {
                float v = acc[r] + bi;
                if (RELU) v = fmaxf(v, 0.f);
                sH[wm * 32 + rt * 16 + q * 4 + r][n] = f2b(v);
            }
        }
    }
}

__global__ __launch_bounds__(256, 3) void ngp_fused(
    const float* __restrict__ pos, const float* __restrict__ dir, const u16* __restrict__ ws,
    const float* __restrict__ b1, const float* __restrict__ b2, const float* __restrict__ b3,
    const float* __restrict__ b4, const float* __restrict__ bc1, const float* __restrict__ bc2,
    float* __restrict__ out) {
    __shared__ __align__(16) u16 sH[64][HP];
    const int t = threadIdx.x;
    const int lane = t & 63;
    const int w = t >> 6;
    const int lr = lane & 15, q = lane >> 4;
    const int wm = w & 1, wn = w >> 1;
    const long rb = (long)blockIdx.x * 64;

    const u16* WT1  = ws;
    const u16* WT2  = ws + 16384;
    const u16* WT3  = ws + 81920;
    const u16* WT4  = ws + 147456;
    const u16* WTc1 = ws + 151552;
    const u16* WTc2 = ws + 159744;

    // ---- positional encoding into sH[r][0..63] ----
    {
        const int r = t & 63;
        const int g = t >> 6;
        const long row = rb + r;
        float xn[3];
#pragma unroll
        for (int c = 0; c < 3; ++c) xn[c] = pos[row * 3 + c] * (1.0f / 1.5f);
        if (g == 3) {
            sH[r][0] = f2b(xn[0]); sH[r][1] = f2b(xn[1]); sH[r][2] = f2b(xn[2]);
            sH[r][63] = 0;
#pragma unroll
            for (int c = 0; c < 3; ++c) {
                float tv = xn[c] * 512.f * INV2PI;  // degree 9
                sH[r][3 + 27 + c]  = f2b(sinrev(tv));
                sH[r][33 + 27 + c] = f2b(sinrev(tv + 0.25f));
            }
        } else {
#pragma unroll
            for (int dd = 0; dd < 3; ++dd) {
                const int d = g * 3 + dd;
                const float sc = (float)(1 << d);
#pragma unroll
                for (int c = 0; c < 3; ++c) {
                    float tv = xn[c] * sc * INV2PI;
                    sH[r][3 + d * 3 + c]  = f2b(sinrev(tv));
                    sH[r][33 + d * 3 + c] = f2b(sinrev(tv + 0.25f));
                }
            }
        }
    }
    __syncthreads();
    dense<64, 8, true>(WT1, b1, sH, wm, lr, q, wn * 128);
    __syncthreads();
    dense<256, 8, true>(WT2, b2, sH, wm, lr, q, wn * 128);
    __syncthreads();
    dense<256, 8, true>(WT3, b3, sH, wm, lr, q, wn * 128);
    __syncthreads();

    // ---- layer 4 (256 -> 16): density to global, feat (cols 1..15) -> sH[r][0..14] ----
    {
        short8 aF[2][8];
        if (wn == 0) {
#pragma unroll
            for (int rt = 0; rt < 2; ++rt)
#pragma unroll
                for (int kt = 0; kt < 8; ++kt)
                    aF[rt][kt] = *(const short8*)&sH[wm * 32 + rt * 16 + lr][kt * 32 + q * 8];
        }
        __syncthreads();
        if (wn == 0) {
            short8 bF[8];
            const u16* wrow = WT4 + lr * 256 + q * 8;
#pragma unroll
            for (int kt = 0; kt < 8; ++kt) bF[kt] = *(const short8*)(wrow + kt * 32);
            const float bi = b4[lr];
#pragma unroll
            for (int rt = 0; rt < 2; ++rt) {
                f32x4 acc = {0.f, 0.f, 0.f, 0.f};
#pragma unroll
                for (int kt = 0; kt < 8; ++kt)
                    acc = __builtin_amdgcn_mfma_f32_16x16x32_bf16(aF[rt][kt], bF[kt], acc, 0, 0, 0);
#pragma unroll
                for (int r = 0; r < 4; ++r) {
                    const float v = acc[r] + bi;
                    const int gm = wm * 32 + rt * 16 + q * 4 + r;
                    if (lr == 0)
                        out[3 * (long)NPTS + rb + gm] = __expf(v - 1.f);
                    else
                        sH[gm][lr - 1] = f2b(v);
                }
            }
        }
        // ---- direction encoding -> sH[r][15..41], zero 42..63 (disjoint cols, no barrier) ----
        {
            const int r = t & 63;
            const int g = t >> 6;
            const long row = rb + r;
            const float dx = dir[row * 3 + 0];
            const float dy = dir[row * 3 + 1];
            const float dz = dir[row * 3 + 2];
            const float nrm = sqrtf(dx * dx + dy * dy + dz * dz);
            const float inv = 1.f / fmaxf(nrm, 1e-12f);
            const float dn[3] = {dx * inv, dy * inv, dz * inv};
            if (g == 0) { sH[r][15] = f2b(dn[0]); sH[r][16] = f2b(dn[1]); sH[r][17] = f2b(dn[2]); }
            const float sc = (float)(1 << g);  // degree = g (0..3)
#pragma unroll
            for (int c = 0; c < 3; ++c) {
                float tv = dn[c] * sc * INV2PI;
                sH[r][18 + g * 3 + c] = f2b(sinrev(tv));
                sH[r][30 + g * 3 + c] = f2b(sinrev(tv + 0.25f));
            }
            for (int j = 42 + g; j < 64; j += 4) sH[r][j] = 0;
        }
    }
    __syncthreads();
    dense<64, 4, true>(WTc1, bc1, sH, wm, lr, q, wn * 64);
    __syncthreads();

    // ---- color head (128 -> 3): sigmoid -> rgb (fp32 out) ----
    if (wn == 0) {
        short8 aF[2][4];
#pragma unroll
        for (int rt = 0; rt < 2; ++rt)
#pragma unroll
            for (int kt = 0; kt < 4; ++kt)
                aF[rt][kt] = *(const short8*)&sH[wm * 32 + rt * 16 + lr][kt * 32 + q * 8];
        short8 bF[4];
        const u16* wrow = WTc2 + lr * 128 + q * 8;
#pragma unroll
        for (int kt = 0; kt < 4; ++kt) bF[kt] = *(const short8*)(wrow + kt * 32);
        const float bi = (lr < 3) ? bc2[lr] : 0.f;
#pragma unroll
        for (int rt = 0; rt < 2; ++rt) {
            f32x4 acc = {0.f, 0.f, 0.f, 0.f};
#pragma unroll
            for (int kt = 0; kt < 4; ++kt)
                acc = __builtin_amdgcn_mfma_f32_16x16x32_bf16(aF[rt][kt], bF[kt], acc, 0, 0, 0);
            if (lr < 3) {
#pragma unroll
                for (int r = 0; r < 4; ++r) {
                    const float v = acc[r] + bi;
                    const float sg = 1.f / (1.f + __expf(-v));
                    const int gm = wm * 32 + rt * 16 + q * 4 + r;
                    out[(rb + gm) * 3 + lr] = sg;
                }
            }
        }
    }
}

extern "C" void kernel_launch(void* const* d_in, const int* in_sizes, int n_in,
                              void* d_out, int out_size, void* d_ws, size_t ws_size,
                              hipStream_t stream) {
    const float* pos = (const float*)d_in[0];
    const float* dir = (const float*)d_in[1];
    const float* W1  = (const float*)d_in[2];
    const float* b1  = (const float*)d_in[3];
    const float* W2  = (const float*)d_in[4];
    const float* b2  = (const float*)d_in[5];
    const float* W3  = (const float*)d_in[6];
    const float* b3  = (const float*)d_in[7];
    const float* W4  = (const float*)d_in[8];
    const float* b4  = (const float*)d_in[9];
    const float* Wc1 = (const float*)d_in[10];
    const float* bc1 = (const float*)d_in[11];
    const float* Wc2 = (const float*)d_in[12];
    const float* bc2 = (const float*)d_in[13];
    u16* ws   = (u16*)d_ws;
    float* out = (float*)d_out;

    prep_weights<<<633, 256, 0, stream>>>(W1, W2, W3, W4, Wc1, Wc2, ws);
    ngp_fused<<<NPTS / 64, 256, 0, stream>>>(pos, dir, ws, b1, b2, b3, b4, bc1, bc2, out);
}

// Round 3
// 765.981 us; speedup vs baseline: 1.5894x; 1.5894x over previous
//
#include <hip/hip_runtime.h>

typedef unsigned short u16;
typedef __attribute__((ext_vector_type(8))) short short8;
typedef __attribute__((ext_vector_type(4))) float f32x4;

#define NPTS 1048576
#define HP 264  // sH row stride in elements (528 B, 16B-aligned)

__device__ __forceinline__ u16 f2b(float f) {
    unsigned int x = __float_as_uint(f);
    return (u16)((x + 0x7fffu + ((x >> 16) & 1u)) >> 16);
}
#define INV2PI 0.15915494309189535f
// sin with argument in revolutions; v_sin_f32 wants fract-reduced input
__device__ __forceinline__ float sinrev(float t) {
    t = t - floorf(t);
    return __builtin_amdgcn_sinf(t);
}

// ---------------- weight convert(fp32->bf16) + transpose/pad prepass ----------------
// ws layout (bf16 elements), WT[n][k] row-major in k:
//  WT1  @      0 : 256 x  64   (from W1  63x256, k>=63 -> 0)
//  WT2  @  16384 : 256 x 256   (from W2 256x256)
//  WT3  @  81920 : 256 x 256   (from W3 256x256)
//  WT4  @ 147456 :  16 x 256   (from W4 256x16)
//  WTc1 @ 151552 : 128 x  64   (from Wc1 42x128, k>=42 -> 0)
//  WTc2 @ 159744 :  16 x 128   (from Wc2 128x3, n>=3 -> 0)
__global__ void prep_weights(const float* __restrict__ W1, const float* __restrict__ W2,
                             const float* __restrict__ W3, const float* __restrict__ W4,
                             const float* __restrict__ Wc1, const float* __restrict__ Wc2,
                             u16* __restrict__ ws) {
    int i = blockIdx.x * 256 + threadIdx.x;
    if (i < 16384) { int n = i >> 6, k = i & 63;  ws[i]          = (k < 63) ? f2b(W1[k * 256 + n]) : (u16)0; return; }
    i -= 16384;
    if (i < 65536) { int n = i >> 8, k = i & 255; ws[16384 + i]  = f2b(W2[k * 256 + n]); return; }
    i -= 65536;
    if (i < 65536) { int n = i >> 8, k = i & 255; ws[81920 + i]  = f2b(W3[k * 256 + n]); return; }
    i -= 65536;
    if (i < 4096)  { int n = i >> 8, k = i & 255; ws[147456 + i] = f2b(W4[k * 16 + n]); return; }
    i -= 4096;
    if (i < 8192)  { int n = i >> 6, k = i & 63;  ws[151552 + i] = (k < 42) ? f2b(Wc1[k * 128 + n]) : (u16)0; return; }
    i -= 8192;
    if (i < 2048)  { int n = i >> 7, k = i & 127; ws[159744 + i] = (n < 3) ? f2b(Wc2[k * 3 + n]) : (u16)0; return; }
}

// ---------------- fused dense layer (chunked-K accumulate) ----------------
// MFMA 16x16x32 bf16.  A frag: m=lane&15, k=(lane>>4)*8+j (contig 16B from sH row)
// B frag: n=lane&15, k=(lane>>4)*8+j (contig 16B from WT[n][k] in global)
// D: col(n)=lane&15, row(m)=(lane>>4)*4+reg.
// Wave handles rows [row0,row0+64) (RT=4) x cols [nbase,nbase+NT*16).
// acc held in AGPRs across K; A-frags re-read per kt chunk. All LDS reads of
// every wave complete before the internal barrier; writes happen after it, so
// the in-place sH update is race-free.
template <int K, int NT, bool RELU>
__device__ __forceinline__ void dense(const u16* __restrict__ WT, const float* __restrict__ bias,
                                      u16 (*sH)[HP], int row0, int nbase, int lr, int q) {
    constexpr int NKT = K / 32;
    f32x4 acc[4][NT];
#pragma unroll
    for (int rt = 0; rt < 4; ++rt)
#pragma unroll
        for (int nt = 0; nt < NT; ++nt) acc[rt][nt] = f32x4{0.f, 0.f, 0.f, 0.f};
#pragma unroll
    for (int kt = 0; kt < NKT; ++kt) {
        short8 aF[4];
#pragma unroll
        for (int rt = 0; rt < 4; ++rt)
            aF[rt] = *(const short8*)&sH[row0 + rt * 16 + lr][kt * 32 + q * 8];
#pragma unroll
        for (int nt = 0; nt < NT; ++nt) {
            const short8 bF = *(const short8*)(WT + (size_t)(nbase + nt * 16 + lr) * K + kt * 32 + q * 8);
#pragma unroll
            for (int rt = 0; rt < 4; ++rt)
                acc[rt][nt] = __builtin_amdgcn_mfma_f32_16x16x32_bf16(aF[rt], bF, acc[rt][nt], 0, 0, 0);
        }
    }
    __syncthreads();
#pragma unroll
    for (int nt = 0; nt < NT; ++nt) {
        const int n = nbase + nt * 16 + lr;
        const float bi = bias[n];
#pragma unroll
        for (int rt = 0; rt < 4; ++rt)
#pragma unroll
            for (int r = 0; r < 4; ++r) {
                float v = acc[rt][nt][r] + bi;
                if (RELU) v = fmaxf(v, 0.f);
                sH[row0 + rt * 16 + q * 4 + r][n] = f2b(v);
            }
    }
}

__global__ __launch_bounds__(512, 4) void ngp_fused(
    const float* __restrict__ pos, const float* __restrict__ dir, const u16* __restrict__ ws,
    const float* __restrict__ b1, const float* __restrict__ b2, const float* __restrict__ b3,
    const float* __restrict__ b4, const float* __restrict__ bc1, const float* __restrict__ bc2,
    float* __restrict__ out) {
    __shared__ __align__(16) u16 sH[128][HP];
    const int t = threadIdx.x;
    const int lane = t & 63;
    const int w = t >> 6;           // 8 waves
    const int lr = lane & 15, q = lane >> 4;
    const int wm = w & 1;           // row half (64 rows each)
    const int wn = w >> 1;          // col quarter
    const long rb = (long)blockIdx.x * 128;

    const u16* WT1  = ws;
    const u16* WT2  = ws + 16384;
    const u16* WT3  = ws + 81920;
    const u16* WT4  = ws + 147456;
    const u16* WTc1 = ws + 151552;
    const u16* WTc2 = ws + 159744;

    // ---- positional encoding into sH[r][0..63] ----
    {
        const int r = t & 127;
        const int g = t >> 7;       // 0..3
        const long row = rb + r;
        float xn[3];
#pragma unroll
        for (int c = 0; c < 3; ++c) xn[c] = pos[row * 3 + c] * (1.0f / 1.5f);
        if (g == 3) {
            sH[r][0] = f2b(xn[0]); sH[r][1] = f2b(xn[1]); sH[r][2] = f2b(xn[2]);
            sH[r][63] = 0;
#pragma unroll
            for (int c = 0; c < 3; ++c) {
                float tv = xn[c] * 512.f * INV2PI;  // degree 9
                sH[r][3 + 27 + c]  = f2b(sinrev(tv));
                sH[r][33 + 27 + c] = f2b(sinrev(tv + 0.25f));
            }
        } else {
#pragma unroll
            for (int dd = 0; dd < 3; ++dd) {
                const int d = g * 3 + dd;
                const float sc = (float)(1 << d);
#pragma unroll
                for (int c = 0; c < 3; ++c) {
                    float tv = xn[c] * sc * INV2PI;
                    sH[r][3 + d * 3 + c]  = f2b(sinrev(tv));
                    sH[r][33 + d * 3 + c] = f2b(sinrev(tv + 0.25f));
                }
            }
        }
    }
    __syncthreads();
    dense<64, 4, true>(WT1, b1, sH, wm * 64, wn * 64, lr, q);
    __syncthreads();
    dense<256, 4, true>(WT2, b2, sH, wm * 64, wn * 64, lr, q);
    __syncthreads();
    dense<256, 4, true>(WT3, b3, sH, wm * 64, wn * 64, lr, q);
    __syncthreads();

    // ---- layer 4 (256 -> 16): all 8 waves, 16 rows each (RT=1, n = lr) ----
    {
        f32x4 acc = {0.f, 0.f, 0.f, 0.f};
#pragma unroll
        for (int kt = 0; kt < 8; ++kt) {
            const short8 aF = *(const short8*)&sH[w * 16 + lr][kt * 32 + q * 8];
            const short8 bF = *(const short8*)(WT4 + lr * 256 + kt * 32 + q * 8);
            acc = __builtin_amdgcn_mfma_f32_16x16x32_bf16(aF, bF, acc, 0, 0, 0);
        }
        __syncthreads();
        {
            const float bi = b4[lr];
#pragma unroll
            for (int r = 0; r < 4; ++r) {
                const float v = acc[r] + bi;
                const int gm = w * 16 + q * 4 + r;
                if (lr == 0)
                    out[3 * (long)NPTS + rb + gm] = __expf(v - 1.f);
                else
                    sH[gm][lr - 1] = f2b(v);   // feat -> cols 0..14
            }
        }
        // ---- direction encoding -> sH[r][15..41], zero 42..63 (cols disjoint from feat) ----
        {
            const int r = t & 127;
            const int g = t >> 7;   // 0..3
            const long row = rb + r;
            const float dx = dir[row * 3 + 0];
            const float dy = dir[row * 3 + 1];
            const float dz = dir[row * 3 + 2];
            const float nrm = sqrtf(dx * dx + dy * dy + dz * dz);
            const float inv = 1.f / fmaxf(nrm, 1e-12f);
            const float dn[3] = {dx * inv, dy * inv, dz * inv};
            if (g == 0) { sH[r][15] = f2b(dn[0]); sH[r][16] = f2b(dn[1]); sH[r][17] = f2b(dn[2]); }
            const float sc = (float)(1 << g);  // degree = g (0..3)
#pragma unroll
            for (int c = 0; c < 3; ++c) {
                float tv = dn[c] * sc * INV2PI;
                sH[r][18 + g * 3 + c] = f2b(sinrev(tv));
                sH[r][30 + g * 3 + c] = f2b(sinrev(tv + 0.25f));
            }
            for (int j = 42 + g; j < 64; j += 4) sH[r][j] = 0;
        }
    }
    __syncthreads();
    dense<64, 2, true>(WTc1, bc1, sH, wm * 64, wn * 32, lr, q);
    __syncthreads();

    // ---- color head (128 -> 3): all 8 waves, 16 rows each, sigmoid -> rgb ----
    {
        f32x4 acc = {0.f, 0.f, 0.f, 0.f};
#pragma unroll
        for (int kt = 0; kt < 4; ++kt) {
            const short8 aF = *(const short8*)&sH[w * 16 + lr][kt * 32 + q * 8];
            const short8 bF = *(const short8*)(WTc2 + lr * 128 + kt * 32 + q * 8);
            acc = __builtin_amdgcn_mfma_f32_16x16x32_bf16(aF, bF, acc, 0, 0, 0);
        }
        if (lr < 3) {
            const float bi = bc2[lr];
#pragma unroll
            for (int r = 0; r < 4; ++r) {
                const float v = acc[r] + bi;
                const float sg = 1.f / (1.f + __expf(-v));
                const int gm = w * 16 + q * 4 + r;
                out[(rb + gm) * 3 + lr] = sg;
            }
        }
    }
}

extern "C" void kernel_launch(void* const* d_in, const int* in_sizes, int n_in,
                              void* d_out, int out_size, void* d_ws, size_t ws_size,
                              hipStream_t stream) {
    const float* pos = (const float*)d_in[0];
    const float* dir = (const float*)d_in[1];
    const float* W1  = (const float*)d_in[2];
    const float* b1  = (const float*)d_in[3];
    const float* W2  = (const float*)d_in[4];
    const float* b2  = (const float*)d_in[5];
    const float* W3  = (const float*)d_in[6];
    const float* b3  = (const float*)d_in[7];
    const float* W4  = (const float*)d_in[8];
    const float* b4  = (const float*)d_in[9];
    const float* Wc1 = (const float*)d_in[10];
    const float* bc1 = (const float*)d_in[11];
    const float* Wc2 = (const float*)d_in[12];
    const float* bc2 = (const float*)d_in[13];
    u16* ws   = (u16*)d_ws;
    float* out = (float*)d_out;

    prep_weights<<<633, 256, 0, stream>>>(W1, W2, W3, W4, Wc1, Wc2, ws);
    ngp_fused<<<NPTS / 128, 512, 0, stream>>>(pos, dir, ws, b1, b2, b3, b4, bc1, bc2, out);
}